// Round 4
// baseline (510.391 us; speedup 1.0000x reference)
//
#include <hip/hip_runtime.h>

// ---------------------------------------------------------------------------
// ZSSR involution net, all fp32.
// conv_in -> 6x [tw_kernel (t+w gen) -> e_kernel (einsum)] -> conv_out+PS
// Round 4: parallelism fix. e_kernel = 1296 one-wave WGs (16x16 tile x
// (group,4ch-slab)); halo 8.4 KB LDS; w from global (L2) hidden by ~5 wv/CU.
// ---------------------------------------------------------------------------

#define H2 130
#define PLANE (H2*H2)          // 16900
#define XBUF (64*PLANE)        // 1,081,600 floats
#define WPLANE (132*132)       // 17424 (padded w plane, 16B-aligned rows)

#define OFF_X0 0
#define OFF_X1 XBUF
#define OFF_WF (2*XBUF)        // w-field: 196*17424 floats

// --- conv_in: 3->64, 3x3, pad=2 : (3,128,128) -> (64,130,130) --------------
__global__ __launch_bounds__(256) void conv_in_kernel(
        const float* __restrict__ inf, const float* __restrict__ W,
        const float* __restrict__ b, float* __restrict__ x0) {
    const int c = blockIdx.y;                       // wave-uniform
    int p = blockIdx.x * 256 + threadIdx.x;
    if (p >= PLANE) return;
    int h = p / H2, w = p % H2;
    float acc = b[c];
    #pragma unroll
    for (int i = 0; i < 3; ++i)
        #pragma unroll
        for (int ky = 0; ky < 3; ++ky) {
            int y = h - 2 + ky;
            if ((unsigned)y >= 128u) continue;
            #pragma unroll
            for (int kx = 0; kx < 3; ++kx) {
                int x = w - 2 + kx;
                if ((unsigned)x >= 128u) continue;
                acc += W[((c*3 + i)*3 + ky)*3 + kx] * inf[i*16384 + y*128 + x];
            }
        }
    x0[c*PLANE + p] = acc;
}

// --- tw_kernel: per-pixel t (shared) + dynamic kernel w --------------------
// 256 thr = 64 px * 4 group-waves. t in LDS, w-field out (padded planes).
__global__ __launch_bounds__(256) void tw_kernel(
        const float* __restrict__ x, float* __restrict__ wf,
        const float* __restrict__ redw,   // [16][64]
        const float* __restrict__ gamma, const float* __restrict__ beta,
        const float* __restrict__ spanw,  // [196][16]
        const float* __restrict__ spanb)  // [196]
{
    __shared__ float t_lds[64*17];
    const int tid = threadIdx.x;
    const int pix = tid & 63;
    const int g = __builtin_amdgcn_readfirstlane(tid >> 6);
    int px = blockIdx.x*64 + pix;
    int pxc = px < PLANE ? px : PLANE-1;

    // phase A: t[4g..4g+3] for this pixel (cooperative across 4 waves)
    const float* rw = redw + g*256;
    float a0=0.f, a1=0.f, a2=0.f, a3=0.f;
    for (int c = 0; c < 64; ++c) {
        float xv = x[c*PLANE + pxc];
        a0 += rw[c]      * xv;
        a1 += rw[64 + c] * xv;
        a2 += rw[128 + c]* xv;
        a3 += rw[192 + c]* xv;
    }
    int r0 = g*4;
    t_lds[pix*17 + r0 + 0] = fmaxf(gamma[r0+0]*a0 + beta[r0+0], 0.f);
    t_lds[pix*17 + r0 + 1] = fmaxf(gamma[r0+1]*a1 + beta[r0+1], 0.f);
    t_lds[pix*17 + r0 + 2] = fmaxf(gamma[r0+2]*a2 + beta[r0+2], 0.f);
    t_lds[pix*17 + r0 + 3] = fmaxf(gamma[r0+3]*a3 + beta[r0+3], 0.f);
    __syncthreads();

    // phase B: 49 w-channels for (pixel, g)
    float t16[16];
    #pragma unroll
    for (int r = 0; r < 16; ++r) t16[r] = t_lds[pix*17 + r];
    const bool ok = px < PLANE;
    int row = pxc / 130, col = pxc % 130;
    const float* sw = spanw + g*49*16;
    const float* sb = spanb + g*49;
    float* wbase = wf + (size_t)(g*49)*WPLANE + row*132 + col;
    #pragma unroll 7
    for (int k = 0; k < 49; ++k) {
        float acc = sb[k];
        #pragma unroll
        for (int r = 0; r < 16; ++r) acc += sw[k*16 + r] * t16[r];
        if (ok) wbase[(size_t)k*WPLANE] = acc;
    }
}

// --- e_kernel v2: per-pixel 7x7 dynamic conv + ReLU ------------------------
// Grid 9 x 9 x 16; blockIdx.z = (group<<2) | chslab. ONE wave per WG.
// Tile 16x16 px; thread = 4-px strip; 4 channels per thread.
// LDS: halo [4ch][22 rows][24 cols] = 8448 B.
__global__ __launch_bounds__(64) void e_kernel(
        const float* __restrict__ x, const float* __restrict__ wf,
        float* __restrict__ xout)
{
    __shared__ float xl[4*528];
    const int tid = threadIdx.x;          // 0..63 = strip id
    const int g  = blockIdx.z >> 2;
    const int c0 = (blockIdx.z & 3) * 4;  // first of 4 channels in slab
    const int ty = blockIdx.y*16, tx = blockIdx.x*16;

    // halo load: 2112 floats / 64 threads = 33 iters (zero-pad OOB + col pads)
    for (int i = tid; i < 4*528; i += 64) {
        int c  = i / 528, rem = i % 528;
        int r  = rem / 24, cl = rem % 24;
        int gy = ty - 3 + r, gx = tx - 3 + cl;
        float v = 0.f;
        if (cl < 22 && (unsigned)gy < (unsigned)H2 && (unsigned)gx < (unsigned)H2)
            v = x[(g*16 + c0 + c)*PLANE + gy*H2 + gx];
        xl[i] = v;
    }
    __syncthreads();

    const int srow = tid >> 2, scol = tid & 3;
    float acc[4][4] = {};

    const float* wrow = wf + (size_t)(g*49)*WPLANE + (ty + srow)*132 + tx + scol*4;
    #pragma unroll
    for (int i = 0; i < 7; ++i) {
        float4 w7[7];
        #pragma unroll
        for (int j = 0; j < 7; ++j)
            w7[j] = *(const float4*)(wrow + (size_t)(i*7 + j)*WPLANE);
        #pragma unroll
        for (int cc = 0; cc < 4; ++cc) {
            const float* xb = &xl[cc*528 + (srow + i)*24 + scol*4];
            float4 xa = *(const float4*)(xb);
            float4 xm = *(const float4*)(xb + 4);
            float4 xz = *(const float4*)(xb + 8);
            float xr[12] = {xa.x,xa.y,xa.z,xa.w, xm.x,xm.y,xm.z,xm.w,
                            xz.x,xz.y,xz.z,xz.w};
            #pragma unroll
            for (int j = 0; j < 7; ++j) {
                acc[cc][0] += w7[j].x * xr[j+0];
                acc[cc][1] += w7[j].y * xr[j+1];
                acc[cc][2] += w7[j].z * xr[j+2];
                acc[cc][3] += w7[j].w * xr[j+3];
            }
        }
    }

    const int h = ty + srow;
    #pragma unroll
    for (int cc = 0; cc < 4; ++cc) {
        float* dst = xout + (size_t)(g*16 + c0 + cc)*PLANE + h*H2 + tx + scol*4;
        #pragma unroll
        for (int q = 0; q < 4; ++q) {
            int w = tx + scol*4 + q;
            if (h < H2 && w < H2) dst[q] = fmaxf(acc[cc][q], 0.f);
        }
    }
}

// --- conv_out (64->12, 3x3 valid) + PixelShuffle(2) ------------------------
__global__ __launch_bounds__(256) void conv_out_ps_kernel(
        const float* __restrict__ x, const float* __restrict__ W,
        const float* __restrict__ b, float* __restrict__ out)
{
    __shared__ float xh[64*120];   // 7680 floats
    __shared__ float wl[6912];     // 12*64*9
    const int tid = threadIdx.x;
    const int ty = blockIdx.y*8, tx = blockIdx.x*8;

    for (int idx = tid; idx < 6912; idx += 256) wl[idx] = W[idx];
    for (int idx = tid; idx < 7680; idx += 256) {
        int c = idx / 120, rem = idx % 120;
        int r = rem / 12, cl = rem % 12;
        float v = 0.f;
        if (cl < 10) v = x[c*PLANE + (ty + r)*H2 + tx + cl];
        xh[idx] = v;
    }
    __syncthreads();

    const int wave = __builtin_amdgcn_readfirstlane(tid >> 6);
    const int lane = tid & 63;
    const int s = lane >> 2, cq = lane & 3;
    const int sr = s >> 1, pc0 = (s & 1)*4;
    float acc[3][4] = {};

    for (int c = cq*16; c < cq*16 + 16; ++c) {
        #pragma unroll
        for (int ky = 0; ky < 3; ++ky) {
            const float* xb = &xh[c*120 + (sr + ky)*12 + pc0];
            float4 xa = *(const float4*)xb;
            float2 xm = *(const float2*)(xb + 4);
            float xr[6] = {xa.x, xa.y, xa.z, xa.w, xm.x, xm.y};
            #pragma unroll
            for (int oj = 0; oj < 3; ++oj) {
                const float* wp = &wl[((wave*3 + oj)*64 + c)*9 + ky*3];
                #pragma unroll
                for (int kx = 0; kx < 3; ++kx) {
                    float wv = wp[kx];
                    #pragma unroll
                    for (int q = 0; q < 4; ++q)
                        acc[oj][q] += wv * xr[kx + q];
                }
            }
        }
    }

    #pragma unroll
    for (int oj = 0; oj < 3; ++oj)
        #pragma unroll
        for (int q = 0; q < 4; ++q) {
            float v = acc[oj][q];
            v += __shfl_xor(v, 1, 64);
            v += __shfl_xor(v, 2, 64);
            acc[oj][q] = v;
        }

    if (cq == 0) {
        #pragma unroll
        for (int oj = 0; oj < 3; ++oj) {
            int o = wave*3 + oj;
            float bo = b[o];
            int c3 = o >> 2, r = (o >> 1) & 1, s2 = o & 1;
            int h = ty + sr;
            #pragma unroll
            for (int q = 0; q < 4; ++q) {
                int w = tx + pc0 + q;
                out[c3*65536 + (2*h + r)*256 + 2*w + s2] = acc[oj][q] + bo;
            }
        }
    }
}

// ---------------------------------------------------------------------------
extern "C" void kernel_launch(void* const* d_in, const int* in_sizes, int n_in,
                              void* d_out, int out_size, void* d_ws, size_t ws_size,
                              hipStream_t stream) {
    const float* inf   = (const float*)d_in[0];
    const float* cinw  = (const float*)d_in[1];
    const float* cinb  = (const float*)d_in[2];
    const float* redw  = (const float*)d_in[3];
    const float* gam   = (const float*)d_in[4];
    const float* bet   = (const float*)d_in[5];
    const float* spw   = (const float*)d_in[6];
    const float* spb   = (const float*)d_in[7];
    const float* cow   = (const float*)d_in[8];
    const float* cob   = (const float*)d_in[9];

    float* ws = (float*)d_ws;
    float* x0 = ws + OFF_X0;
    float* x1 = ws + OFF_X1;
    float* wfield = ws + OFF_WF;

    conv_in_kernel<<<dim3((PLANE + 255)/256, 64), 256, 0, stream>>>(
        inf, cinw, cinb, x0);

    float* cur = x0; float* nxt = x1;
    for (int l = 0; l < 6; ++l) {
        tw_kernel<<<(PLANE + 63)/64, 256, 0, stream>>>(
            cur, wfield,
            redw + l*1024, gam + l*16, bet + l*16,
            spw + l*3136, spb + l*196);
        e_kernel<<<dim3(9, 9, 16), 64, 0, stream>>>(cur, wfield, nxt);
        float* t = cur; cur = nxt; nxt = t;
    }

    conv_out_ps_kernel<<<dim3(16, 16), 256, 0, stream>>>(
        cur, cow, cob, (float*)d_out);
}

// Round 5
// 429.847 us; speedup vs baseline: 1.1874x; 1.1874x over previous
//
#include <hip/hip_runtime.h>

// ---------------------------------------------------------------------------
// ZSSR involution net, all fp32.
// conv_in -> 6x [t_kernel (reduction+BN+ReLU) -> e_kernel (w-gen in LDS +
// einsum)] -> conv_out+PixelShuffle.
// Round 5: kill the 13.7MB w-field (54MB redundant HBM/L3 traffic measured in
// round 4). w computed on the fly from a 1.7MB t-field and staged in LDS.
// ---------------------------------------------------------------------------

#define H2 130
#define PLANE (H2*H2)          // 16900
#define XBUF (64*PLANE)        // 1,081,600 floats

#define OFF_X0 0
#define OFF_X1 XBUF
#define OFF_TF (2*XBUF)        // t-field: PLANE*16 floats, layout [px][16]

// --- conv_in: 3->64, 3x3, pad=2 : (3,128,128) -> (64,130,130) --------------
__global__ __launch_bounds__(256) void conv_in_kernel(
        const float* __restrict__ inf, const float* __restrict__ W,
        const float* __restrict__ b, float* __restrict__ x0) {
    const int c = blockIdx.y;                       // wave-uniform
    int p = blockIdx.x * 256 + threadIdx.x;
    if (p >= PLANE) return;
    int h = p / H2, w = p % H2;
    float acc = b[c];
    #pragma unroll
    for (int i = 0; i < 3; ++i)
        #pragma unroll
        for (int ky = 0; ky < 3; ++ky) {
            int y = h - 2 + ky;
            if ((unsigned)y >= 128u) continue;
            #pragma unroll
            for (int kx = 0; kx < 3; ++kx) {
                int x = w - 2 + kx;
                if ((unsigned)x >= 128u) continue;
                acc += W[((c*3 + i)*3 + ky)*3 + kx] * inf[i*16384 + y*128 + x];
            }
        }
    x0[c*PLANE + p] = acc;
}

// --- t_kernel: t[px][16] = relu(bn(redw @ x[:,px])) ------------------------
// 256 thr = 64 px * 4 r-quad waves; coalesced x reads, float4 t writes.
__global__ __launch_bounds__(256) void t_kernel(
        const float* __restrict__ x, float* __restrict__ tf,
        const float* __restrict__ redw,   // [16][64]
        const float* __restrict__ gamma, const float* __restrict__ beta)
{
    const int tid = threadIdx.x;
    const int pix = tid & 63;
    const int rq = __builtin_amdgcn_readfirstlane(tid >> 6);  // wave-uniform
    int px = blockIdx.x*64 + pix;
    int pxc = px < PLANE ? px : PLANE-1;

    const float* rw = redw + rq*4*64;
    float a0=0.f, a1=0.f, a2=0.f, a3=0.f;
    for (int c = 0; c < 64; ++c) {
        float xv = x[c*PLANE + pxc];
        a0 += rw[c]      * xv;
        a1 += rw[64 + c] * xv;
        a2 += rw[128 + c]* xv;
        a3 += rw[192 + c]* xv;
    }
    if (px < PLANE) {
        int r0 = rq*4;
        float4 t4;
        t4.x = fmaxf(gamma[r0+0]*a0 + beta[r0+0], 0.f);
        t4.y = fmaxf(gamma[r0+1]*a1 + beta[r0+1], 0.f);
        t4.z = fmaxf(gamma[r0+2]*a2 + beta[r0+2], 0.f);
        t4.w = fmaxf(gamma[r0+3]*a3 + beta[r0+3], 0.f);
        *(float4*)(tf + px*16 + r0) = t4;
    }
}

// --- e_kernel v3: w-gen (LDS) + 7x7 dynamic conv + ReLU --------------------
// Grid (9,17,4): 16x8 px tile, group = blockIdx.z. WG = 128 thr (2 waves).
// LDS: x halo [16ch][14r][24c] 21.5KB + w_lds[49][128px] 25KB = 46.6KB
// -> 3 WGs/CU. Einsum: thread = (strip of 4px, ch-quad), all-LDS b128 reads.
#define TW 16
#define TH 8
#define HR 14          // TH+6
#define HC 24          // 22 used cols, padded to 24 for b128 alignment
__global__ __launch_bounds__(128) void e_kernel(
        const float* __restrict__ x, const float* __restrict__ tf,
        const float* __restrict__ spanw,  // [196][16] (group-major)
        const float* __restrict__ spanb,  // [196]
        float* __restrict__ xout)
{
    __shared__ float xl[16*HR*HC];   // 21504 B
    __shared__ float wl[49*128];     // 25088 B
    const int tid = threadIdx.x;
    const int g  = blockIdx.z;
    const int ty = blockIdx.y*TH, tx = blockIdx.x*TW;

    // phase 1: halo load (issued first; latency hidden behind w-gen FMAs)
    for (int i = tid; i < 16*HR*22; i += 128) {
        int c  = i / (HR*22), rem = i % (HR*22);
        int r  = rem / 22,  cl = rem % 22;
        int gy = ty - 3 + r, gx = tx - 3 + cl;
        float v = 0.f;
        if ((unsigned)gy < (unsigned)H2 && (unsigned)gx < (unsigned)H2)
            v = x[(g*16 + c)*PLANE + gy*H2 + gx];
        xl[c*(HR*HC) + r*HC + cl] = v;
    }

    // phase 2: per-pixel w[49] from t-field -> LDS
    {
        const int prow = tid >> 4, pcol = tid & 15;
        int h = ty + prow, w = tx + pcol;
        int hc = h < H2 ? h : H2-1, wc = w < H2 ? w : H2-1;
        const float* tp = tf + (hc*H2 + wc)*16;
        float t16[16];
        float4 ta = *(const float4*)(tp);
        float4 tb = *(const float4*)(tp + 4);
        float4 tc = *(const float4*)(tp + 8);
        float4 td = *(const float4*)(tp + 12);
        t16[0]=ta.x; t16[1]=ta.y; t16[2]=ta.z; t16[3]=ta.w;
        t16[4]=tb.x; t16[5]=tb.y; t16[6]=tb.z; t16[7]=tb.w;
        t16[8]=tc.x; t16[9]=tc.y; t16[10]=tc.z; t16[11]=tc.w;
        t16[12]=td.x; t16[13]=td.y; t16[14]=td.z; t16[15]=td.w;
        const float* sw = spanw + g*49*16;    // wave-uniform -> scalar loads
        const float* sb = spanb + g*49;
        #pragma unroll 7
        for (int k = 0; k < 49; ++k) {
            float acc = sb[k];
            #pragma unroll
            for (int r = 0; r < 16; ++r) acc += sw[k*16 + r] * t16[r];
            wl[k*128 + tid] = acc;
        }
    }
    __syncthreads();

    // phase 3: einsum. strip = 4 consecutive px, 4 channels per thread.
    const int strip = tid & 31, cq = tid >> 5;
    const int srow = strip >> 2, scol = strip & 3;
    const int c0 = cq*4;
    float acc[4][4] = {};

    #pragma unroll
    for (int i = 0; i < 7; ++i) {
        float4 w7[7];
        #pragma unroll
        for (int j = 0; j < 7; ++j)
            w7[j] = *(const float4*)&wl[(i*7 + j)*128 + srow*16 + scol*4];
        #pragma unroll
        for (int cc = 0; cc < 4; ++cc) {
            const float* xb = &xl[(c0 + cc)*(HR*HC) + (srow + i)*HC + scol*4];
            float4 xa = *(const float4*)(xb);
            float4 xm = *(const float4*)(xb + 4);
            float4 xz = *(const float4*)(xb + 8);
            float xr[12] = {xa.x,xa.y,xa.z,xa.w, xm.x,xm.y,xm.z,xm.w,
                            xz.x,xz.y,xz.z,xz.w};
            #pragma unroll
            for (int j = 0; j < 7; ++j) {
                acc[cc][0] += w7[j].x * xr[j+0];
                acc[cc][1] += w7[j].y * xr[j+1];
                acc[cc][2] += w7[j].z * xr[j+2];
                acc[cc][3] += w7[j].w * xr[j+3];
            }
        }
    }

    const int h = ty + srow;
    #pragma unroll
    for (int cc = 0; cc < 4; ++cc) {
        float* dst = xout + (size_t)(g*16 + c0 + cc)*PLANE + h*H2 + tx + scol*4;
        #pragma unroll
        for (int q = 0; q < 4; ++q) {
            int w = tx + scol*4 + q;
            if (h < H2 && w < H2) dst[q] = fmaxf(acc[cc][q], 0.f);
        }
    }
}

// --- conv_out (64->12, 3x3 valid) + PixelShuffle(2) ------------------------
__global__ __launch_bounds__(256) void conv_out_ps_kernel(
        const float* __restrict__ x, const float* __restrict__ W,
        const float* __restrict__ b, float* __restrict__ out)
{
    __shared__ float xh[64*120];   // 7680 floats
    __shared__ float wl[6912];     // 12*64*9
    const int tid = threadIdx.x;
    const int ty = blockIdx.y*8, tx = blockIdx.x*8;

    for (int idx = tid; idx < 6912; idx += 256) wl[idx] = W[idx];
    for (int idx = tid; idx < 7680; idx += 256) {
        int c = idx / 120, rem = idx % 120;
        int r = rem / 12, cl = rem % 12;
        float v = 0.f;
        if (cl < 10) v = x[c*PLANE + (ty + r)*H2 + tx + cl];
        xh[idx] = v;
    }
    __syncthreads();

    const int wave = __builtin_amdgcn_readfirstlane(tid >> 6);
    const int lane = tid & 63;
    const int s = lane >> 2, cq = lane & 3;
    const int sr = s >> 1, pc0 = (s & 1)*4;
    float acc[3][4] = {};

    for (int c = cq*16; c < cq*16 + 16; ++c) {
        #pragma unroll
        for (int ky = 0; ky < 3; ++ky) {
            const float* xb = &xh[c*120 + (sr + ky)*12 + pc0];
            float4 xa = *(const float4*)xb;
            float2 xm = *(const float2*)(xb + 4);
            float xr[6] = {xa.x, xa.y, xa.z, xa.w, xm.x, xm.y};
            #pragma unroll
            for (int oj = 0; oj < 3; ++oj) {
                const float* wp = &wl[((wave*3 + oj)*64 + c)*9 + ky*3];
                #pragma unroll
                for (int kx = 0; kx < 3; ++kx) {
                    float wv = wp[kx];
                    #pragma unroll
                    for (int q = 0; q < 4; ++q)
                        acc[oj][q] += wv * xr[kx + q];
                }
            }
        }
    }

    #pragma unroll
    for (int oj = 0; oj < 3; ++oj)
        #pragma unroll
        for (int q = 0; q < 4; ++q) {
            float v = acc[oj][q];
            v += __shfl_xor(v, 1, 64);
            v += __shfl_xor(v, 2, 64);
            acc[oj][q] = v;
        }

    if (cq == 0) {
        #pragma unroll
        for (int oj = 0; oj < 3; ++oj) {
            int o = wave*3 + oj;
            float bo = b[o];
            int c3 = o >> 2, r = (o >> 1) & 1, s2 = o & 1;
            int h = ty + sr;
            #pragma unroll
            for (int q = 0; q < 4; ++q) {
                int w = tx + pc0 + q;
                out[c3*65536 + (2*h + r)*256 + 2*w + s2] = acc[oj][q] + bo;
            }
        }
    }
}

// ---------------------------------------------------------------------------
extern "C" void kernel_launch(void* const* d_in, const int* in_sizes, int n_in,
                              void* d_out, int out_size, void* d_ws, size_t ws_size,
                              hipStream_t stream) {
    const float* inf   = (const float*)d_in[0];
    const float* cinw  = (const float*)d_in[1];
    const float* cinb  = (const float*)d_in[2];
    const float* redw  = (const float*)d_in[3];
    const float* gam   = (const float*)d_in[4];
    const float* bet   = (const float*)d_in[5];
    const float* spw   = (const float*)d_in[6];
    const float* spb   = (const float*)d_in[7];
    const float* cow   = (const float*)d_in[8];
    const float* cob   = (const float*)d_in[9];

    float* ws = (float*)d_ws;
    float* x0 = ws + OFF_X0;
    float* x1 = ws + OFF_X1;
    float* tfield = ws + OFF_TF;

    conv_in_kernel<<<dim3((PLANE + 255)/256, 64), 256, 0, stream>>>(
        inf, cinw, cinb, x0);

    float* cur = x0; float* nxt = x1;
    for (int l = 0; l < 6; ++l) {
        t_kernel<<<(PLANE + 63)/64, 256, 0, stream>>>(
            cur, tfield, redw + l*1024, gam + l*16, bet + l*16);
        e_kernel<<<dim3(9, 17, 4), 128, 0, stream>>>(
            cur, tfield, spw + l*3136, spb + l*196, nxt);
        float* t = cur; cur = nxt; nxt = t;
    }

    conv_out_ps_kernel<<<dim3(16, 16), 256, 0, stream>>>(
        cur, cow, cob, (float*)d_out);
}

// Round 6
// 327.921 us; speedup vs baseline: 1.5564x; 1.3108x over previous
//
#include <hip/hip_runtime.h>

// ---------------------------------------------------------------------------
// ZSSR involution net, fp32. Round 6: latency-war edition.
// Layout: feature maps x[g][136*136 px][16 ch] channel-last with 3-px ZERO
// border (so the 7x7 einsum needs no bounds checks), re-zeroed every launch.
// e_kernel: 4624 waves (18/CU), no halo staging, direct L1 float4 taps.
// ---------------------------------------------------------------------------

#define HH 130
#define PLANE (HH*HH)        // 16900
#define SP 136               // padded row stride (130 + 2*3)
#define PPL (SP*SP)          // 18496
#define GP (PPL*16)          // 295,936 floats per group-plane
#define XBUF2 (4*GP)         // 1,183,744 floats per feature buffer
#define OFF_TF (2*XBUF2)     // t-field: PLANE*16 floats [px][16]

// --- zero the 3-px borders of both ping-pong buffers (ws is poisoned) ------
__global__ __launch_bounds__(256) void zero_border_kernel(float* ws) {
    int idx = blockIdx.x*256 + threadIdx.x;     // 1596 border px * 32
    if (idx >= 1596*32) return;
    int q = idx & 3, g = (idx>>2)&3, bsel = (idx>>4)&1, e = idx>>5;
    int r, c;
    if (e < 816) { r = e/136; c = e%136; if (r >= 3) r += 130; }
    else { int j = e-816; r = 3 + j/6; int m = j%6; c = (m<3) ? m : m+130; }
    float4* p = (float4*)(ws + (size_t)bsel*XBUF2 + (size_t)g*GP
                          + ((size_t)r*SP + c)*16 + q*4);
    *p = make_float4(0.f,0.f,0.f,0.f);
}

// --- conv_in: 3->64, 3x3, pad=2 -> x[g][pad px][16] ------------------------
__global__ __launch_bounds__(256) void conv_in_kernel(
        const float* __restrict__ inf, const float* __restrict__ W,
        const float* __restrict__ b, float* __restrict__ x0) {
    __shared__ float wl[448];          // [16 ch][27 taps] + bias[16]
    const int g = blockIdx.y;
    const int tid = threadIdx.x;
    for (int i = tid; i < 448; i += 256)
        wl[i] = (i < 432) ? W[g*432 + i] : b[g*16 + (i-432)];
    __syncthreads();
    int px = blockIdx.x*256 + tid;
    int pxc = px < PLANE ? px : PLANE-1;
    int h = pxc/130, w = pxc%130;
    float xv[27];
    #pragma unroll
    for (int i = 0; i < 3; ++i)
      #pragma unroll
      for (int ky = 0; ky < 3; ++ky) {
        int y = h - 2 + ky;
        #pragma unroll
        for (int kx = 0; kx < 3; ++kx) {
            int xx = w - 2 + kx;
            float v = 0.f;
            if ((unsigned)y < 128u && (unsigned)xx < 128u)
                v = inf[i*16384 + y*128 + xx];
            xv[i*9 + ky*3 + kx] = v;
        }
      }
    float acc[16];
    #pragma unroll
    for (int c = 0; c < 16; ++c) {
        float a = wl[432 + c];
        #pragma unroll
        for (int t = 0; t < 27; ++t) a += wl[c*27 + t] * xv[t];
        acc[c] = a;
    }
    if (px < PLANE) {
        float* dst = x0 + (size_t)g*GP + ((size_t)(h+3)*SP + (w+3))*16;
        #pragma unroll
        for (int q = 0; q < 4; ++q)
            *(float4*)(dst + q*4) =
                make_float4(acc[q*4], acc[q*4+1], acc[q*4+2], acc[q*4+3]);
    }
}

// --- t_kernel: t[px][16] = relu(bn(redw @ x[:,px])) ------------------------
__global__ __launch_bounds__(256) void t_kernel(
        const float* __restrict__ x, float* __restrict__ tf,
        const float* __restrict__ redw,   // [16][64]
        const float* __restrict__ gamma, const float* __restrict__ beta)
{
    const int tid = threadIdx.x;
    const int pix = tid & 63;
    const int rq = __builtin_amdgcn_readfirstlane(tid >> 6);  // wave-uniform
    int px = blockIdx.x*64 + pix;
    int pxc = px < PLANE ? px : PLANE-1;
    int h = pxc/130, w = pxc%130;
    const float* xb = x + ((size_t)(h+3)*SP + (w+3))*16;
    const float* rw = redw + rq*4*64;
    float a0=0.f, a1=0.f, a2=0.f, a3=0.f;
    #pragma unroll
    for (int g = 0; g < 4; ++g) {
        #pragma unroll
        for (int q = 0; q < 4; ++q) {
            float4 v = *(const float4*)(xb + (size_t)g*GP + q*4);
            int c = g*16 + q*4;
            a0 += rw[c]*v.x     + rw[c+1]*v.y     + rw[c+2]*v.z     + rw[c+3]*v.w;
            a1 += rw[64+c]*v.x  + rw[65+c]*v.y    + rw[66+c]*v.z    + rw[67+c]*v.w;
            a2 += rw[128+c]*v.x + rw[129+c]*v.y   + rw[130+c]*v.z   + rw[131+c]*v.w;
            a3 += rw[192+c]*v.x + rw[193+c]*v.y   + rw[194+c]*v.z   + rw[195+c]*v.w;
        }
    }
    if (px < PLANE) {
        int r0 = rq*4;
        float4 t4;
        t4.x = fmaxf(gamma[r0+0]*a0 + beta[r0+0], 0.f);
        t4.y = fmaxf(gamma[r0+1]*a1 + beta[r0+1], 0.f);
        t4.z = fmaxf(gamma[r0+2]*a2 + beta[r0+2], 0.f);
        t4.w = fmaxf(gamma[r0+3]*a3 + beta[r0+3], 0.f);
        *(float4*)(tf + (size_t)px*16 + r0) = t4;
    }
}

// --- e_kernel v4: w-gen (LDS) + 7x7 dynamic conv, direct global taps -------
// Grid (17,17,4): 8x8 px tile, g = blockIdx.z. 256 thr = 64 px * 4 cq.
// LDS: wl[49][68] only (13.3 KB). 4624 waves total.
__global__ __launch_bounds__(256, 4) void e_kernel(
        const float* __restrict__ x, const float* __restrict__ tf,
        const float* __restrict__ spanw,  // [196][16]
        const float* __restrict__ spanb,  // [196]
        float* __restrict__ xout)
{
    __shared__ float wl[49*68];
    const int tid = threadIdx.x;
    const int pxl = tid >> 2, cq = tid & 3;
    const int g = blockIdx.z;
    const int sr = pxl >> 3, sc = pxl & 7;
    const int h = blockIdx.y*8 + sr, w = blockIdx.x*8 + sc;
    const int hc = h < HH ? h : HH-1, wc = w < HH ? w : HH-1;

    // phase 1: per-pixel w[49] from t-field, split 13/12/12/12 across cq
    {
        const float* tp = tf + ((size_t)hc*130 + wc)*16;
        float t16[16];
        #pragma unroll
        for (int q = 0; q < 4; ++q) {
            float4 v = *(const float4*)(tp + q*4);
            t16[q*4]=v.x; t16[q*4+1]=v.y; t16[q*4+2]=v.z; t16[q*4+3]=v.w;
        }
        const float* sw = spanw + g*784;
        const float* sb = spanb + g*49;
        const int k0 = cq*12 + (cq ? 1 : 0);   // 0,13,25,37
        const int kn = cq ? 12 : 13;
        for (int j = 0; j < 13; ++j) {
            if (j < kn) {
                int k = k0 + j;
                float4 s0 = *(const float4*)(sw + k*16);
                float4 s1 = *(const float4*)(sw + k*16 + 4);
                float4 s2 = *(const float4*)(sw + k*16 + 8);
                float4 s3 = *(const float4*)(sw + k*16 + 12);
                float a = sb[k];
                a += s0.x*t16[0] + s0.y*t16[1] + s0.z*t16[2] + s0.w*t16[3];
                a += s1.x*t16[4] + s1.y*t16[5] + s1.z*t16[6] + s1.w*t16[7];
                a += s2.x*t16[8] + s2.y*t16[9] + s2.z*t16[10] + s2.w*t16[11];
                a += s3.x*t16[12] + s3.y*t16[13] + s3.z*t16[14] + s3.w*t16[15];
                wl[k*68 + pxl] = a;
            }
        }
    }
    __syncthreads();

    // phase 2: 49 taps, 4 channels; zero border -> no bounds checks
    const float* xb = x + (size_t)g*GP + ((size_t)hc*SP + wc)*16 + cq*4;
    float4 acc = make_float4(0.f,0.f,0.f,0.f);
    #pragma unroll
    for (int i = 0; i < 7; ++i) {
        const float* xr = xb + (size_t)i*SP*16;
        #pragma unroll
        for (int j = 0; j < 7; ++j) {
            float4 v = *(const float4*)(xr + j*16);
            float wk = wl[(i*7 + j)*68 + pxl];
            acc.x += wk*v.x; acc.y += wk*v.y; acc.z += wk*v.z; acc.w += wk*v.w;
        }
    }
    if (h < HH && w < HH) {
        float4 o;
        o.x = fmaxf(acc.x, 0.f); o.y = fmaxf(acc.y, 0.f);
        o.z = fmaxf(acc.z, 0.f); o.w = fmaxf(acc.w, 0.f);
        *(float4*)(xout + (size_t)g*GP + ((size_t)(h+3)*SP + (w+3))*16 + cq*4) = o;
    }
}

// --- conv_out (64->12, 3x3 valid) + PixelShuffle(2) ------------------------
// LDS transpose-stage from channel-last global, then round-5 compute.
__global__ __launch_bounds__(256) void conv_out_ps_kernel(
        const float* __restrict__ x, const float* __restrict__ W,
        const float* __restrict__ b, float* __restrict__ out)
{
    __shared__ float xh[64*120];   // [c][10 r][12 cl]
    __shared__ float wl[6912];     // 12*64*9
    const int tid = threadIdx.x;
    const int ty = blockIdx.y*8, tx = blockIdx.x*8;

    for (int idx = tid; idx < 6912; idx += 256) wl[idx] = W[idx];
    for (int idx = tid; idx < 1600; idx += 256) {
        int g = idx/400, rem = idx%400;
        int p100 = rem>>2, q = rem&3;
        int r = p100/10, cl = p100%10;
        float4 v = *(const float4*)(x + (size_t)g*GP
                     + ((size_t)(ty + r + 3)*SP + tx + cl + 3)*16 + q*4);
        int c0 = g*16 + q*4;
        xh[(c0+0)*120 + r*12 + cl] = v.x;
        xh[(c0+1)*120 + r*12 + cl] = v.y;
        xh[(c0+2)*120 + r*12 + cl] = v.z;
        xh[(c0+3)*120 + r*12 + cl] = v.w;
    }
    __syncthreads();

    const int wave = __builtin_amdgcn_readfirstlane(tid >> 6);
    const int lane = tid & 63;
    const int s = lane >> 2, cq = lane & 3;
    const int sr = s >> 1, pc0 = (s & 1)*4;
    float acc[3][4] = {};

    for (int c = cq*16; c < cq*16 + 16; ++c) {
        #pragma unroll
        for (int ky = 0; ky < 3; ++ky) {
            const float* xb = &xh[c*120 + (sr + ky)*12 + pc0];
            float4 xa = *(const float4*)xb;
            float2 xm = *(const float2*)(xb + 4);
            float xr[6] = {xa.x, xa.y, xa.z, xa.w, xm.x, xm.y};
            #pragma unroll
            for (int oj = 0; oj < 3; ++oj) {
                const float* wp = &wl[((wave*3 + oj)*64 + c)*9 + ky*3];
                #pragma unroll
                for (int kx = 0; kx < 3; ++kx) {
                    float wv = wp[kx];
                    #pragma unroll
                    for (int q = 0; q < 4; ++q)
                        acc[oj][q] += wv * xr[kx + q];
                }
            }
        }
    }

    #pragma unroll
    for (int oj = 0; oj < 3; ++oj)
        #pragma unroll
        for (int q = 0; q < 4; ++q) {
            float v = acc[oj][q];
            v += __shfl_xor(v, 1, 64);
            v += __shfl_xor(v, 2, 64);
            acc[oj][q] = v;
        }

    if (cq == 0) {
        #pragma unroll
        for (int oj = 0; oj < 3; ++oj) {
            int o = wave*3 + oj;
            float bo = b[o];
            int c3 = o >> 2, r = (o >> 1) & 1, s2 = o & 1;
            int h = ty + sr;
            #pragma unroll
            for (int q = 0; q < 4; ++q) {
                int w = tx + pc0 + q;
                out[c3*65536 + (2*h + r)*256 + 2*w + s2] = acc[oj][q] + bo;
            }
        }
    }
}

// ---------------------------------------------------------------------------
extern "C" void kernel_launch(void* const* d_in, const int* in_sizes, int n_in,
                              void* d_out, int out_size, void* d_ws, size_t ws_size,
                              hipStream_t stream) {
    const float* inf   = (const float*)d_in[0];
    const float* cinw  = (const float*)d_in[1];
    const float* cinb  = (const float*)d_in[2];
    const float* redw  = (const float*)d_in[3];
    const float* gam   = (const float*)d_in[4];
    const float* bet   = (const float*)d_in[5];
    const float* spw   = (const float*)d_in[6];
    const float* spb   = (const float*)d_in[7];
    const float* cow   = (const float*)d_in[8];
    const float* cob   = (const float*)d_in[9];

    float* ws = (float*)d_ws;
    float* x0 = ws;
    float* x1 = ws + XBUF2;
    float* tfield = ws + OFF_TF;

    zero_border_kernel<<<(1596*32 + 255)/256, 256, 0, stream>>>(ws);

    conv_in_kernel<<<dim3((PLANE + 255)/256, 4), 256, 0, stream>>>(
        inf, cinw, cinb, x0);

    float* cur = x0; float* nxt = x1;
    for (int l = 0; l < 6; ++l) {
        t_kernel<<<(PLANE + 63)/64, 256, 0, stream>>>(
            cur, tfield, redw + l*1024, gam + l*16, bet + l*16);
        e_kernel<<<dim3(17, 17, 4), 256, 0, stream>>>(
            cur, tfield, spw + l*3136, spb + l*196, nxt);
        float* t = cur; cur = nxt; nxt = t;
    }

    conv_out_ps_kernel<<<dim3(16, 16), 256, 0, stream>>>(
        cur, cow, cob, (float*)d_out);
}